// Round 1
// 959.045 us; speedup vs baseline: 1.1986x; 1.1986x over previous
//
#include <hip/hip_runtime.h>
#include <cstdint>
#include <cstddef>

// fstgcn on MI355X — round 5:
//  (1) k_gemm_adj staging: reg-staged ds_write -> __builtin_amdgcn_global_load_lds
//      width=16 (VALUBusy 28.8% > MfmaUtil 16.7% said staging VALU dominated).
//  (2) adaptive window batching: grid was 384 blocks = 1.5 blocks/CU
//      (Occupancy 15.4% == grid cap). Pick max G in [1,9] fitting ws_size.
// Output fp32, Yw/maxT fp32 (precision margin kept from round 4).

typedef __bf16 bf16;
typedef float f32x4 __attribute__((ext_vector_type(4)));
typedef __bf16 bf16x8 __attribute__((ext_vector_type(8)));

constexpr int T_  = 12;
constexpr int N_  = 1024;
constexpr int C_  = 64;
constexpr int NW_ = 9;
constexpr long long SLAB_ = 2048LL * 1024LL;  // 2M elems: one [bc][n] or [b][n][c] slab

// canonical small-weights block (bf16), element offsets
constexpr int OF_ADJ  = 0;            // 1024*4096
constexpr int OF_TEMB = 4194304;      // 768
constexpr int OF_SEMB = 4195072;      // 65536
constexpr int OF_C1W  = 4260608;      // 32768
constexpr int OF_C1B  = 4293376;      // 128
constexpr int OF_GW   = 4293504;      // 221184
constexpr int OF_GB   = 4514688;      // 3456
constexpr int OF_END  = 4518144;

static __device__ __forceinline__ float sigmoidf_(float x) {
  return __builtin_amdgcn_rcpf(1.0f + __expf(-x));
}

// async global->LDS, 16B per lane; lds ptr must be wave-uniform chunk base
static __device__ __forceinline__ void g2l16(const bf16* g, bf16* l) {
  __builtin_amdgcn_global_load_lds(
      (const __attribute__((address_space(1))) void*)g,
      (__attribute__((address_space(3))) void*)l, 16, 0, 0);
}

// ------------------------------------------------------------ dtype detector (insurance)
__global__ __launch_bounds__(256)
void k_detect(const void* __restrict__ data_raw, int* __restrict__ flag)
{
  __shared__ int cnt;
  const int tid = threadIdx.x;
  if (tid == 0) cnt = 0;
  __syncthreads();
  const uint32_t* W = (const uint32_t*)data_raw;
  int local = 0;
  for (int s = 0; s < 32; s++) {
    const uint32_t w = W[tid * 32 + s];
    const int e8 = (int)((w >> 7) & 0xFF);
    local += (e8 < 97 || e8 > 157) ? 1 : 0;
  }
  atomicAdd(&cnt, local);
  __syncthreads();
  if (tid == 0) *flag = (cnt > 2458) ? 1 : 0;     // >30% weird low-half exponent -> fp32
}

static __device__ __forceinline__ float rd_(const void* p, long long i, int isF32) {
  return isF32 ? ((const float*)p)[i] : (float)((const bf16*)p)[i];
}

// ------------------------------------------------------------ canonicalize weights to bf16
__global__ __launch_bounds__(256)
void k_convert(const void* adj, const void* temb, const void* semb,
               const void* c1w, const void* c1b, const void* gw, const void* gb,
               const int* __restrict__ flagp, bf16* __restrict__ canon)
{
  const int isF32 = *flagp;
  const int e = blockIdx.x * 256 + threadIdx.x;
  float v;
  if      (e < OF_TEMB) v = rd_(adj,  e,           isF32);
  else if (e < OF_SEMB) v = rd_(temb, e - OF_TEMB, isF32);
  else if (e < OF_C1W)  v = rd_(semb, e - OF_SEMB, isF32);
  else if (e < OF_C1B)  v = rd_(c1w,  e - OF_C1W,  isF32);
  else if (e < OF_GW)   v = rd_(c1b,  e - OF_C1B,  isF32);
  else if (e < OF_GB)   v = rd_(gw,   e - OF_GW,   isF32);
  else                  v = rd_(gb,   e - OF_GB,   isF32);
  canon[e] = (bf16)v;
}

// ------------------------------------------------------------ prep x slabs (group)
// xg[s][bc][n] = bf16(data[b][tbase+s][n][c] + temb + semb),  bc = b*64+c
__global__ __launch_bounds__(256)
void k_prepg(const void* __restrict__ data_raw, const int* __restrict__ flagp,
             const bf16* __restrict__ temb, const bf16* __restrict__ semb,
             bf16* __restrict__ xg, int tbase)
{
  const int isF32 = *flagp;
  const int s  = blockIdx.z;
  const int t  = tbase + s;
  const int bc = blockIdx.y * 256 + threadIdx.x;
  const int n0 = blockIdx.x * 128;
  const int b = bc >> 6, c = bc & 63;
  const float te = (float)temb[t * C_ + c];
  const long long dbase = ((long long)(b * T_ + t) * N_) * C_ + c;
  bf16* op = xg + (size_t)s * SLAB_ + (size_t)bc * N_ + n0;
  for (int i = 0; i < 128; i += 8) {
    bf16x8 v;
#pragma unroll
    for (int u = 0; u < 8; u++) {
      const int n = n0 + i + u;
      const float dv = rd_(data_raw, dbase + (long long)n * C_, isF32);
      v[u] = (bf16)(dv + te + (float)semb[n * C_ + c]);
    }
    *(bf16x8*)&op[i] = v;
  }
}

// ------------------------------------------------------------ weight transposes
__global__ __launch_bounds__(256)
void k_wprep(const bf16* __restrict__ conv1w, const bf16* __restrict__ gcnw,
             bf16* __restrict__ Wt, bf16* __restrict__ gwT)
{
  const int idx = blockIdx.x * 256 + threadIdx.x;
  if (idx < 128 * 256) {               // Wt[c2][kidx], kidx = k*64 + ci
    const int c2 = idx >> 8, kidx = idx & 255;
    const int ci = kidx & 63, k = kidx >> 6;
    Wt[idx] = conv1w[c2 * 256 + ci * 4 + k];
  }
  const int i2 = idx - 128 * 256;
  if (i2 >= 0 && i2 < 27 * 8192) {     // gwT[wj][d][c] = gcn_w[wj][c][d]
    const int wj = i2 >> 13, r = i2 & 8191;
    const int d = r >> 6, c = r & 63;
    gwT[i2] = gcnw[wj * 8192 + c * 128 + d];
  }
}

// ------------------------------------------------------------ adjacency GEMM
// MODE 0 (wing):  init 0,        store fp32 -> outF
// MODE 1 (layer): init fp32 Yw,  store bf16 -> outB
// Staging: global_load_lds width=16; LDS layout [row][32] bf16 linear, so
// chunk ch (16 rows = 1024B) gets lane l's 16B at row ch*16+(l>>2), k8=(l&3)*8.
template<int MODE>
__global__ __launch_bounds__(256)
void k_gemm_adj(const bf16* __restrict__ Aadj, const bf16* __restrict__ Bop,
                const float* __restrict__ initY, float* __restrict__ outF,
                bf16* __restrict__ outB, int Ksize)
{
  const int lw = blockIdx.z;
  const int m0 = blockIdx.y * 128;     // n_out tile
  const int c0 = blockIdx.x * 128;     // bc tile
  const int tid = threadIdx.x;
  const int lane = tid & 63, wid = tid >> 6;
  const int lrow = lane & 15, q = lane >> 4;
  const int wm = wid >> 1, wn = wid & 1;

  __shared__ __align__(16) bf16 lsA[128 * 32];
  __shared__ __align__(16) bf16 lsB[128 * 32];

  // per-lane source coords for global_load_lds staging
  const int srow = lane >> 2;          // row within a 16-row chunk
  const int sk8  = (lane & 3) * 8;     // elem offset within the 32-elem K slice

  f32x4 acc[4][4];
  const size_t woff = (size_t)lw * SLAB_;
  if (MODE == 1) {
#pragma unroll
    for (int i = 0; i < 4; i++)
#pragma unroll
      for (int j = 0; j < 4; j++) {
        const int col = c0 + wn * 64 + j * 16 + lrow;
        const int b = col >> 6, c = col & 63;
        const float* yp = initY + woff + (size_t)b * (N_ * C_)
                        + (size_t)(m0 + wm * 64 + i * 16 + q * 4) * C_ + c;
#pragma unroll
        for (int r = 0; r < 4; r++) acc[i][j][r] = yp[(size_t)r * C_];
      }
  } else {
#pragma unroll
    for (int i = 0; i < 4; i++)
#pragma unroll
      for (int j = 0; j < 4; j++)
#pragma unroll
        for (int r = 0; r < 4; r++) acc[i][j][r] = 0.0f;
  }

  const bf16* Bw = Bop + (size_t)lw * SLAB_;
  for (int k0 = 0; k0 < Ksize; k0 += 32) {
    const int tblk = k0 >> 10;
    const int kloc = k0 & 1023;
    const bf16* Bt = Bw + (size_t)tblk * SLAB_ + kloc;
    const bf16* At = Aadj + k0;
#pragma unroll
    for (int s = 0; s < 2; s++) {
      const int ch  = s * 4 + wid;               // chunk 0..7 (wave-uniform)
      const int row = ch * 16 + srow;
      g2l16(&At[(size_t)(m0 + row) * 4096 + sk8], &lsA[ch * 512]);
      g2l16(&Bt[(size_t)(c0 + row) * N_   + sk8], &lsB[ch * 512]);
    }
    __syncthreads();                              // drains vmcnt before reads
    bf16x8 af[4], bfv[4];
#pragma unroll
    for (int i = 0; i < 4; i++) af[i]  = *(const bf16x8*)&lsA[(wm * 64 + i * 16 + lrow) * 32 + q * 8];
#pragma unroll
    for (int j = 0; j < 4; j++) bfv[j] = *(const bf16x8*)&lsB[(wn * 64 + j * 16 + lrow) * 32 + q * 8];
#pragma unroll
    for (int i = 0; i < 4; i++)
#pragma unroll
      for (int j = 0; j < 4; j++)
        acc[i][j] = __builtin_amdgcn_mfma_f32_16x16x32_bf16(af[i], bfv[j], acc[i][j], 0, 0, 0);
    __syncthreads();
  }

#pragma unroll
  for (int i = 0; i < 4; i++)
#pragma unroll
    for (int j = 0; j < 4; j++) {
      const int col = c0 + wn * 64 + j * 16 + lrow;
      const int b = col >> 6, c = col & 63;
      const size_t base = woff + (size_t)b * (N_ * C_)
                        + (size_t)(m0 + wm * 64 + i * 16 + q * 4) * C_ + c;
      if (MODE == 0) {
#pragma unroll
        for (int r = 0; r < 4; r++) outF[base + (size_t)r * C_] = acc[i][j][r];
      } else {
#pragma unroll
        for (int r = 0; r < 4; r++) outB[base + (size_t)r * C_] = (bf16)acc[i][j][r];
      }
    }
}

// ------------------------------------------------------------ z GEMM (Z^T) + GLU + max
__global__ __launch_bounds__(256)
void k_zglu(const bf16* __restrict__ tbuf, const bf16* __restrict__ gwT,
            const bf16* __restrict__ gcnb, bf16* __restrict__ curT,
            float* __restrict__ maxT, int j, int wbase)
{
  const int lw = blockIdx.z;
  const int wj = (wbase + lw) * 3 + j;
  const int tid = threadIdx.x;
  const int lane = tid & 63, wid = tid >> 6;
  const int lrow = lane & 15, q = lane >> 4;
  const int nb0 = blockIdx.x * 128 + wid * 32;

  const bf16* Ab = gwT + (size_t)wj * (128 * 64);
  const bf16* Bb = tbuf + (size_t)lw * SLAB_;

  f32x4 acc[8][2];
#pragma unroll
  for (int rt = 0; rt < 8; rt++)
#pragma unroll
    for (int ct = 0; ct < 2; ct++)
#pragma unroll
      for (int r = 0; r < 4; r++) acc[rt][ct][r] = 0.0f;

#pragma unroll
  for (int ks = 0; ks < 2; ks++) {
    bf16x8 bv[2];
#pragma unroll
    for (int ct = 0; ct < 2; ct++)
      bv[ct] = *(const bf16x8*)&Bb[(size_t)(nb0 + ct * 16 + lrow) * C_ + ks * 32 + q * 8];
#pragma unroll
    for (int rt = 0; rt < 8; rt++) {
      const bf16x8 av = *(const bf16x8*)&Ab[(rt * 16 + lrow) * C_ + ks * 32 + q * 8];
#pragma unroll
      for (int ct = 0; ct < 2; ct++)
        acc[rt][ct] = __builtin_amdgcn_mfma_f32_16x16x32_bf16(av, bv[ct], acc[rt][ct], 0, 0, 0);
    }
  }

  const bf16* bias = gcnb + (size_t)wj * 128;
#pragma unroll
  for (int rt = 0; rt < 4; rt++)
#pragma unroll
    for (int ct = 0; ct < 2; ct++) {
      const int nb = nb0 + ct * 16 + lrow;
      const int b = nb >> 10, n = nb & 1023;
#pragma unroll
      for (int r = 0; r < 4; r++) {
        const int d = rt * 16 + q * 4 + r;
        const float zL = acc[rt][ct][r]     + (float)bias[d];
        const float zR = acc[rt + 4][ct][r] + (float)bias[d + 64];
        const float cur = zL * sigmoidf_(zR);
        const size_t addr = (size_t)lw * SLAB_ + (size_t)(b * 64 + d) * N_ + n;
        curT[addr] = (bf16)cur;
        if (j == 0) {
          maxT[addr] = cur;
        } else {
          maxT[addr] = fmaxf(maxT[addr], cur);
        }
      }
    }
}

// ------------------------------------------------------------ conv GEMM + GLU + max add
__global__ __launch_bounds__(256)
void k_final(const void* __restrict__ data_raw, const int* __restrict__ flagp,
             const bf16* __restrict__ Wt, const bf16* __restrict__ convb,
             const float* __restrict__ maxT, float* __restrict__ out, int wbase)
{
  const int isF32 = *flagp;
  const int lw = blockIdx.z;
  const int w = wbase + lw;
  const int bbat = blockIdx.y;
  const int tid = threadIdx.x;
  const int lane = tid & 63, wid = tid >> 6;
  const int lrow = lane & 15, q = lane >> 4;
  const int n0 = blockIdx.x * 128 + wid * 32;

  f32x4 acc[2][8];
#pragma unroll
  for (int rt = 0; rt < 2; rt++)
#pragma unroll
    for (int ct = 0; ct < 8; ct++)
#pragma unroll
      for (int r = 0; r < 4; r++) acc[rt][ct][r] = 0.0f;

#pragma unroll
  for (int s = 0; s < 8; s++) {                 // kidx = s*32 + q*8 + u = k*64 + ci
    const int k = s >> 1, ci0 = (s & 1) * 32;
    bf16x8 av[2];
#pragma unroll
    for (int rt = 0; rt < 2; rt++) {
      const long long off =
        ((long long)((bbat * T_ + w + k) * N_) + n0 + rt * 16 + lrow) * C_ + ci0 + q * 8;
      if (!isF32) {
        av[rt] = *(const bf16x8*)&((const bf16*)data_raw)[off];
      } else {
        const float* p = (const float*)data_raw + off;
        bf16x8 v;
#pragma unroll
        for (int u = 0; u < 8; u++) v[u] = (bf16)p[u];
        av[rt] = v;
      }
    }
#pragma unroll
    for (int ct = 0; ct < 8; ct++) {
      const bf16x8 bv = *(const bf16x8*)&Wt[(ct * 16 + lrow) * 256 + s * 32 + q * 8];
#pragma unroll
      for (int rt = 0; rt < 2; rt++)
        acc[rt][ct] = __builtin_amdgcn_mfma_f32_16x16x32_bf16(av[rt], bv, acc[rt][ct], 0, 0, 0);
    }
  }

#pragma unroll
  for (int rt = 0; rt < 2; rt++)
#pragma unroll
    for (int ctL = 0; ctL < 4; ctL++) {
      const int cL = ctL * 16 + lrow;
      const float bL = (float)convb[cL], bR = (float)convb[cL + 64];
#pragma unroll
      for (int r = 0; r < 4; r++) {
        const int n = n0 + rt * 16 + q * 4 + r;
        const float zL = acc[rt][ctL][r] + bL;
        const float zR = acc[rt][ctL + 4][r] + bR;
        const float res = sigmoidf_(zL) * zR;
        const float mv = maxT[(size_t)lw * SLAB_ + (size_t)(bbat * 64 + cL) * N_ + n];
        out[(size_t)((bbat * NW_ + w) * N_ + n) * C_ + cL] = res + mv;
      }
    }
}

// ------------------------------------------------------------ launcher
extern "C" void kernel_launch(void* const* d_in, const int* in_sizes, int n_in,
                              void* d_out, int out_size, void* d_ws, size_t ws_size,
                              hipStream_t stream)
{
  (void)in_sizes; (void)n_in; (void)out_size;
  const void* data   = d_in[1];
  const void* adj    = d_in[2];
  const void* temb   = d_in[3];
  const void* semb   = d_in[4];
  const void* conv1w = d_in[5];
  const void* conv1b = d_in[6];
  const void* gcnw   = d_in[7];
  const void* gcnb   = d_in[8];
  float* out = (float*)d_out;   // fp32 output per reference dtype

  // adaptive window batching: pick max G in [1,9] whose footprint fits ws_size.
  // footprint(G) ~= 9.5MB + (G+3)*4MiB (xg) + 24*G MiB (Yw+tbuf+curT+maxT)
  int G = 1;
  for (int g = 9; g >= 2; g--) {
    size_t need = 256;
    auto pad = [&](size_t x) { need += (x + 255) & ~(size_t)255; };
    pad((size_t)OF_END * 2);              // canon
    pad((size_t)(g + 3) * SLAB_ * 2);     // xg
    pad((size_t)g * SLAB_ * 4);           // Yw  (fp32)
    pad((size_t)g * SLAB_ * 2);           // tbuf
    pad((size_t)g * SLAB_ * 2);           // curT
    pad((size_t)g * SLAB_ * 4);           // maxT (fp32)
    pad(128 * 256 * 2);                   // Wt
    pad(27 * 8192 * 2);                   // gwT
    if (need <= ws_size) { G = g; break; }
  }

  char* ws = (char*)d_ws;
  int* flag = (int*)ws;
  size_t off = 256;
  auto allocB = [&](size_t bytes) -> char* {
    char* p = ws + off;
    off += (bytes + 255) & ~(size_t)255;
    return p;
  };
  bf16*  canon = (bf16*) allocB((size_t)OF_END * 2);
  bf16*  xg    = (bf16*) allocB((size_t)(G + 3) * SLAB_ * 2);
  float* Yw    = (float*)allocB((size_t)G * SLAB_ * 4);
  bf16*  tbuf  = (bf16*) allocB((size_t)G * SLAB_ * 2);
  bf16*  curT  = (bf16*) allocB((size_t)G * SLAB_ * 2);
  float* maxT  = (float*)allocB((size_t)G * SLAB_ * 4);
  bf16*  Wt    = (bf16*) allocB(128 * 256 * 2);
  bf16*  gwT   = (bf16*) allocB(27 * 8192 * 2);

  const bf16* adjC  = canon + OF_ADJ;
  const bf16* tembC = canon + OF_TEMB;
  const bf16* sembC = canon + OF_SEMB;
  const bf16* c1wC  = canon + OF_C1W;
  const bf16* c1bC  = canon + OF_C1B;
  const bf16* gwC   = canon + OF_GW;
  const bf16* gbC   = canon + OF_GB;

  k_detect<<<dim3(1), 256, 0, stream>>>(data, flag);
  k_convert<<<dim3(OF_END / 256), 256, 0, stream>>>(adj, temb, semb, conv1w, conv1b,
                                                    gcnw, gcnb, flag, canon);
  k_wprep<<<dim3(992), 256, 0, stream>>>(c1wC, gwC, Wt, gwT);

  for (int wbase = 0; wbase < NW_; wbase += G) {
    const int gc = (NW_ - wbase < G) ? (NW_ - wbase) : G;

    k_prepg<<<dim3(8, 8, gc + 3), 256, 0, stream>>>(data, flag, tembC, sembC, xg, wbase);

    // wing: Yw = adj[:, :3N] @ x[w..w+3)   (fp32 out)
    k_gemm_adj<0><<<dim3(16, 8, gc), 256, 0, stream>>>(adjC, xg, nullptr, Yw, nullptr, 3072);

    for (int j = 0; j < 3; j++) {
      const bf16* Bop = (j == 0) ? (xg + 3 * SLAB_) : curT;
      k_gemm_adj<1><<<dim3(16, 8, gc), 256, 0, stream>>>(adjC + 3072, Bop, Yw, nullptr, tbuf, 1024);
      k_zglu<<<dim3(256, 1, gc), 256, 0, stream>>>(tbuf, gwT, gbC, curT, maxT, j, wbase);
    }

    k_final<<<dim3(8, 32, gc), 256, 0, stream>>>(data, flag, Wt, c1bC, maxT, out, wbase);
  }
}

// Round 2
// 938.255 us; speedup vs baseline: 1.2252x; 1.0222x over previous
//
#include <hip/hip_runtime.h>
#include <cstdint>
#include <cstddef>

// fstgcn on MI355X — round 6:
//  (1) k_gemm_adj: T3-minimal double-buffered prefetch — STAGE(next) issued
//      BEFORE compute(cur), one barrier per K-step. Round-5 counters showed
//      full stage latency on the critical path (MfmaUtil 26%, no pipe >50%).
//  (2) k_gemm_adj: T2 XOR swizzle, both-sides-or-neither (rule 21): linear
//      LDS dest, inverse-swizzled global SOURCE for global_load_lds, swizzled
//      ds_read. Kills the 8-way q-group conflict (14.2M conflict cycles).
//  (3) k_zglu: skip dead curT store at j==2; k_final: f32x4 vector loads.

typedef __bf16 bf16;
typedef float f32x4 __attribute__((ext_vector_type(4)));
typedef __bf16 bf16x8 __attribute__((ext_vector_type(8)));

constexpr int T_  = 12;
constexpr int N_  = 1024;
constexpr int C_  = 64;
constexpr int NW_ = 9;
constexpr long long SLAB_ = 2048LL * 1024LL;  // 2M elems: one [bc][n] or [b][n][c] slab

// canonical small-weights block (bf16), element offsets
constexpr int OF_ADJ  = 0;            // 1024*4096
constexpr int OF_TEMB = 4194304;      // 768
constexpr int OF_SEMB = 4195072;      // 65536
constexpr int OF_C1W  = 4260608;      // 32768
constexpr int OF_C1B  = 4293376;      // 128
constexpr int OF_GW   = 4293504;      // 221184
constexpr int OF_GB   = 4514688;      // 3456
constexpr int OF_END  = 4518144;

static __device__ __forceinline__ float sigmoidf_(float x) {
  return __builtin_amdgcn_rcpf(1.0f + __expf(-x));
}

// async global->LDS, 16B per lane; lds ptr must be wave-uniform chunk base
static __device__ __forceinline__ void g2l16(const bf16* g, bf16* l) {
  __builtin_amdgcn_global_load_lds(
      (const __attribute__((address_space(1))) void*)g,
      (__attribute__((address_space(3))) void*)l, 16, 0, 0);
}

// ------------------------------------------------------------ dtype detector (insurance)
__global__ __launch_bounds__(256)
void k_detect(const void* __restrict__ data_raw, int* __restrict__ flag)
{
  __shared__ int cnt;
  const int tid = threadIdx.x;
  if (tid == 0) cnt = 0;
  __syncthreads();
  const uint32_t* W = (const uint32_t*)data_raw;
  int local = 0;
  for (int s = 0; s < 32; s++) {
    const uint32_t w = W[tid * 32 + s];
    const int e8 = (int)((w >> 7) & 0xFF);
    local += (e8 < 97 || e8 > 157) ? 1 : 0;
  }
  atomicAdd(&cnt, local);
  __syncthreads();
  if (tid == 0) *flag = (cnt > 2458) ? 1 : 0;     // >30% weird low-half exponent -> fp32
}

static __device__ __forceinline__ float rd_(const void* p, long long i, int isF32) {
  return isF32 ? ((const float*)p)[i] : (float)((const bf16*)p)[i];
}

// ------------------------------------------------------------ canonicalize weights to bf16
__global__ __launch_bounds__(256)
void k_convert(const void* adj, const void* temb, const void* semb,
               const void* c1w, const void* c1b, const void* gw, const void* gb,
               const int* __restrict__ flagp, bf16* __restrict__ canon)
{
  const int isF32 = *flagp;
  const int e = blockIdx.x * 256 + threadIdx.x;
  float v;
  if      (e < OF_TEMB) v = rd_(adj,  e,           isF32);
  else if (e < OF_SEMB) v = rd_(temb, e - OF_TEMB, isF32);
  else if (e < OF_C1W)  v = rd_(semb, e - OF_SEMB, isF32);
  else if (e < OF_C1B)  v = rd_(c1w,  e - OF_C1W,  isF32);
  else if (e < OF_GW)   v = rd_(c1b,  e - OF_C1B,  isF32);
  else if (e < OF_GB)   v = rd_(gw,   e - OF_GW,   isF32);
  else                  v = rd_(gb,   e - OF_GB,   isF32);
  canon[e] = (bf16)v;
}

// ------------------------------------------------------------ prep x slabs (group)
// xg[s][bc][n] = bf16(data[b][tbase+s][n][c] + temb + semb),  bc = b*64+c
__global__ __launch_bounds__(256)
void k_prepg(const void* __restrict__ data_raw, const int* __restrict__ flagp,
             const bf16* __restrict__ temb, const bf16* __restrict__ semb,
             bf16* __restrict__ xg, int tbase)
{
  const int isF32 = *flagp;
  const int s  = blockIdx.z;
  const int t  = tbase + s;
  const int bc = blockIdx.y * 256 + threadIdx.x;
  const int n0 = blockIdx.x * 128;
  const int b = bc >> 6, c = bc & 63;
  const float te = (float)temb[t * C_ + c];
  const long long dbase = ((long long)(b * T_ + t) * N_) * C_ + c;
  bf16* op = xg + (size_t)s * SLAB_ + (size_t)bc * N_ + n0;
  for (int i = 0; i < 128; i += 8) {
    bf16x8 v;
#pragma unroll
    for (int u = 0; u < 8; u++) {
      const int n = n0 + i + u;
      const float dv = rd_(data_raw, dbase + (long long)n * C_, isF32);
      v[u] = (bf16)(dv + te + (float)semb[n * C_ + c]);
    }
    *(bf16x8*)&op[i] = v;
  }
}

// ------------------------------------------------------------ weight transposes
__global__ __launch_bounds__(256)
void k_wprep(const bf16* __restrict__ conv1w, const bf16* __restrict__ gcnw,
             bf16* __restrict__ Wt, bf16* __restrict__ gwT)
{
  const int idx = blockIdx.x * 256 + threadIdx.x;
  if (idx < 128 * 256) {               // Wt[c2][kidx], kidx = k*64 + ci
    const int c2 = idx >> 8, kidx = idx & 255;
    const int ci = kidx & 63, k = kidx >> 6;
    Wt[idx] = conv1w[c2 * 256 + ci * 4 + k];
  }
  const int i2 = idx - 128 * 256;
  if (i2 >= 0 && i2 < 27 * 8192) {     // gwT[wj][d][c] = gcn_w[wj][c][d]
    const int wj = i2 >> 13, r = i2 & 8191;
    const int d = r >> 6, c = r & 63;
    gwT[i2] = gcnw[wj * 8192 + c * 128 + d];
  }
}

// ------------------------------------------------------------ adjacency GEMM
// MODE 0 (wing):  init 0,        store fp32 -> outF
// MODE 1 (layer): init fp32 Yw,  store bf16 -> outB
//
// LDS tile [128 rows][32 k] bf16 per buffer, double-buffered (32 KB total).
// Swizzle (rule 21: both sides): physical 16B slot p of row r holds logical
// k-slot p ^ s(r), s(r) = (r&3)^((r>>2)&3).
//   write: global_load_lds dest is linear (lane l -> row ch*16+(l>>2),
//          pslot l&3); SOURCE fetches logical slot (l&3)^s(row) instead.
//   read:  logical slot q of row r read at pslot q^s(r).
// Both s() terms reduce to per-lane constants (rows are 16-aligned per group).
template<int MODE>
__global__ __launch_bounds__(256)
void k_gemm_adj(const bf16* __restrict__ Aadj, const bf16* __restrict__ Bop,
                const float* __restrict__ initY, float* __restrict__ outF,
                bf16* __restrict__ outB, int Ksize)
{
  const int lw = blockIdx.z;
  const int m0 = blockIdx.y * 128;     // n_out tile
  const int c0 = blockIdx.x * 128;     // bc tile
  const int tid = threadIdx.x;
  const int lane = tid & 63, wid = tid >> 6;
  const int lrow = lane & 15, q = lane >> 4;
  const int wm = wid >> 1, wn = wid & 1;

  __shared__ __align__(16) bf16 lsA[2][128 * 32];
  __shared__ __align__(16) bf16 lsB[2][128 * 32];

  // staging source coords (per-lane constants)
  const int srow = lane >> 2;                                    // row in 16-row chunk
  const int sl_w = ((lane >> 2) & 3) ^ ((lane >> 4) & 3);        // s(row) for writes
  const int skel = ((lane & 3) ^ sl_w) * 8;                      // swizzled src k-elem

  // read-side swizzle (per-lane constant)
  const int sl_r  = (lrow & 3) ^ (lrow >> 2);                    // s(row) for reads
  const int rdoff = ((q ^ sl_r) & 3) * 8;                        // swizzled k-elem in row

  const bf16* Bw = Bop + (size_t)lw * SLAB_;

  auto STAGE = [&](int buf, int k0) {
    const int tblk = k0 >> 10;
    const int kloc = k0 & 1023;
    const bf16* Bt = Bw + (size_t)tblk * SLAB_ + kloc;
    const bf16* At = Aadj + k0;
#pragma unroll
    for (int s = 0; s < 2; s++) {
      const int ch  = s * 4 + wid;               // chunk 0..7 (wave-uniform)
      const int row = ch * 16 + srow;
      g2l16(&At[(size_t)(m0 + row) * 4096 + skel], &lsA[buf][ch * 512]);
      g2l16(&Bt[(size_t)(c0 + row) * N_   + skel], &lsB[buf][ch * 512]);
    }
  };

  // prologue: stage tile 0; overlap acc init with its latency
  STAGE(0, 0);

  f32x4 acc[4][4];
  const size_t woff = (size_t)lw * SLAB_;
  if (MODE == 1) {
#pragma unroll
    for (int i = 0; i < 4; i++)
#pragma unroll
      for (int j = 0; j < 4; j++) {
        const int col = c0 + wn * 64 + j * 16 + lrow;
        const int b = col >> 6, c = col & 63;
        const float* yp = initY + woff + (size_t)b * (N_ * C_)
                        + (size_t)(m0 + wm * 64 + i * 16 + q * 4) * C_ + c;
#pragma unroll
        for (int r = 0; r < 4; r++) acc[i][j][r] = yp[(size_t)r * C_];
      }
  } else {
#pragma unroll
    for (int i = 0; i < 4; i++)
#pragma unroll
      for (int j = 0; j < 4; j++)
#pragma unroll
        for (int r = 0; r < 4; r++) acc[i][j][r] = 0.0f;
  }

  __syncthreads();

  int cur = 0;
  for (int k0 = 0; k0 < Ksize; k0 += 32) {
    // prefetch next K-tile into the other buffer BEFORE computing this one;
    // the barrier's vmcnt drain then lands after the MFMA phase.
    if (k0 + 32 < Ksize) STAGE(cur ^ 1, k0 + 32);

    bf16x8 af[4], bfv[4];
#pragma unroll
    for (int i = 0; i < 4; i++)
      af[i]  = *(const bf16x8*)&lsA[cur][(wm * 64 + i * 16 + lrow) * 32 + rdoff];
#pragma unroll
    for (int j = 0; j < 4; j++)
      bfv[j] = *(const bf16x8*)&lsB[cur][(wn * 64 + j * 16 + lrow) * 32 + rdoff];
#pragma unroll
    for (int i = 0; i < 4; i++)
#pragma unroll
      for (int j = 0; j < 4; j++)
        acc[i][j] = __builtin_amdgcn_mfma_f32_16x16x32_bf16(af[i], bfv[j], acc[i][j], 0, 0, 0);

    __syncthreads();
    cur ^= 1;
  }

#pragma unroll
  for (int i = 0; i < 4; i++)
#pragma unroll
    for (int j = 0; j < 4; j++) {
      const int col = c0 + wn * 64 + j * 16 + lrow;
      const int b = col >> 6, c = col & 63;
      const size_t base = woff + (size_t)b * (N_ * C_)
                        + (size_t)(m0 + wm * 64 + i * 16 + q * 4) * C_ + c;
      if (MODE == 0) {
#pragma unroll
        for (int r = 0; r < 4; r++) outF[base + (size_t)r * C_] = acc[i][j][r];
      } else {
#pragma unroll
        for (int r = 0; r < 4; r++) outB[base + (size_t)r * C_] = (bf16)acc[i][j][r];
      }
    }
}

// ------------------------------------------------------------ z GEMM (Z^T) + GLU + max
__global__ __launch_bounds__(256)
void k_zglu(const bf16* __restrict__ tbuf, const bf16* __restrict__ gwT,
            const bf16* __restrict__ gcnb, bf16* __restrict__ curT,
            float* __restrict__ maxT, int j, int wbase)
{
  const int lw = blockIdx.z;
  const int wj = (wbase + lw) * 3 + j;
  const int tid = threadIdx.x;
  const int lane = tid & 63, wid = tid >> 6;
  const int lrow = lane & 15, q = lane >> 4;
  const int nb0 = blockIdx.x * 128 + wid * 32;

  const bf16* Ab = gwT + (size_t)wj * (128 * 64);
  const bf16* Bb = tbuf + (size_t)lw * SLAB_;

  f32x4 acc[8][2];
#pragma unroll
  for (int rt = 0; rt < 8; rt++)
#pragma unroll
    for (int ct = 0; ct < 2; ct++)
#pragma unroll
      for (int r = 0; r < 4; r++) acc[rt][ct][r] = 0.0f;

#pragma unroll
  for (int ks = 0; ks < 2; ks++) {
    bf16x8 bv[2];
#pragma unroll
    for (int ct = 0; ct < 2; ct++)
      bv[ct] = *(const bf16x8*)&Bb[(size_t)(nb0 + ct * 16 + lrow) * C_ + ks * 32 + q * 8];
#pragma unroll
    for (int rt = 0; rt < 8; rt++) {
      const bf16x8 av = *(const bf16x8*)&Ab[(rt * 16 + lrow) * C_ + ks * 32 + q * 8];
#pragma unroll
      for (int ct = 0; ct < 2; ct++)
        acc[rt][ct] = __builtin_amdgcn_mfma_f32_16x16x32_bf16(av, bv[ct], acc[rt][ct], 0, 0, 0);
    }
  }

  const bf16* bias = gcnb + (size_t)wj * 128;
#pragma unroll
  for (int rt = 0; rt < 4; rt++)
#pragma unroll
    for (int ct = 0; ct < 2; ct++) {
      const int nb = nb0 + ct * 16 + lrow;
      const int b = nb >> 10, n = nb & 1023;
#pragma unroll
      for (int r = 0; r < 4; r++) {
        const int d = rt * 16 + q * 4 + r;
        const float zL = acc[rt][ct][r]     + (float)bias[d];
        const float zR = acc[rt + 4][ct][r] + (float)bias[d + 64];
        const float cur = zL * sigmoidf_(zR);
        const size_t addr = (size_t)lw * SLAB_ + (size_t)(b * 64 + d) * N_ + n;
        if (j < 2) curT[addr] = (bf16)cur;     // j==2 curT is dead
        if (j == 0) {
          maxT[addr] = cur;
        } else {
          maxT[addr] = fmaxf(maxT[addr], cur);
        }
      }
    }
}

// ------------------------------------------------------------ conv GEMM + GLU + max add
__global__ __launch_bounds__(256)
void k_final(const void* __restrict__ data_raw, const int* __restrict__ flagp,
             const bf16* __restrict__ Wt, const bf16* __restrict__ convb,
             const float* __restrict__ maxT, float* __restrict__ out, int wbase)
{
  const int isF32 = *flagp;
  const int lw = blockIdx.z;
  const int w = wbase + lw;
  const int bbat = blockIdx.y;
  const int tid = threadIdx.x;
  const int lane = tid & 63, wid = tid >> 6;
  const int lrow = lane & 15, q = lane >> 4;
  const int n0 = blockIdx.x * 128 + wid * 32;

  f32x4 acc[2][8];
#pragma unroll
  for (int rt = 0; rt < 2; rt++)
#pragma unroll
    for (int ct = 0; ct < 8; ct++)
#pragma unroll
      for (int r = 0; r < 4; r++) acc[rt][ct][r] = 0.0f;

#pragma unroll
  for (int s = 0; s < 8; s++) {                 // kidx = s*32 + q*8 + u = k*64 + ci
    const int k = s >> 1, ci0 = (s & 1) * 32;
    bf16x8 av[2];
#pragma unroll
    for (int rt = 0; rt < 2; rt++) {
      const long long off =
        ((long long)((bbat * T_ + w + k) * N_) + n0 + rt * 16 + lrow) * C_ + ci0 + q * 8;
      if (!isF32) {
        av[rt] = *(const bf16x8*)&((const bf16*)data_raw)[off];
      } else {
        const float* p = (const float*)data_raw + off;
        const f32x4 v0 = *(const f32x4*)p;
        const f32x4 v1 = *(const f32x4*)(p + 4);
        bf16x8 v;
#pragma unroll
        for (int u = 0; u < 4; u++) { v[u] = (bf16)v0[u]; v[u + 4] = (bf16)v1[u]; }
        av[rt] = v;
      }
    }
#pragma unroll
    for (int ct = 0; ct < 8; ct++) {
      const bf16x8 bv = *(const bf16x8*)&Wt[(ct * 16 + lrow) * 256 + s * 32 + q * 8];
#pragma unroll
      for (int rt = 0; rt < 2; rt++)
        acc[rt][ct] = __builtin_amdgcn_mfma_f32_16x16x32_bf16(av[rt], bv, acc[rt][ct], 0, 0, 0);
    }
  }

#pragma unroll
  for (int rt = 0; rt < 2; rt++)
#pragma unroll
    for (int ctL = 0; ctL < 4; ctL++) {
      const int cL = ctL * 16 + lrow;
      const float bL = (float)convb[cL], bR = (float)convb[cL + 64];
#pragma unroll
      for (int r = 0; r < 4; r++) {
        const int n = n0 + rt * 16 + q * 4 + r;
        const float zL = acc[rt][ctL][r] + bL;
        const float zR = acc[rt][ctL + 4][r] + bR;
        const float res = sigmoidf_(zL) * zR;
        const float mv = maxT[(size_t)lw * SLAB_ + (size_t)(bbat * 64 + cL) * N_ + n];
        out[(size_t)((bbat * NW_ + w) * N_ + n) * C_ + cL] = res + mv;
      }
    }
}

// ------------------------------------------------------------ launcher
extern "C" void kernel_launch(void* const* d_in, const int* in_sizes, int n_in,
                              void* d_out, int out_size, void* d_ws, size_t ws_size,
                              hipStream_t stream)
{
  (void)in_sizes; (void)n_in; (void)out_size;
  const void* data   = d_in[1];
  const void* adj    = d_in[2];
  const void* temb   = d_in[3];
  const void* semb   = d_in[4];
  const void* conv1w = d_in[5];
  const void* conv1b = d_in[6];
  const void* gcnw   = d_in[7];
  const void* gcnb   = d_in[8];
  float* out = (float*)d_out;   // fp32 output per reference dtype

  // adaptive window batching: pick max G in [1,9] whose footprint fits ws_size.
  int G = 1;
  for (int g = 9; g >= 2; g--) {
    size_t need = 256;
    auto pad = [&](size_t x) { need += (x + 255) & ~(size_t)255; };
    pad((size_t)OF_END * 2);              // canon
    pad((size_t)(g + 3) * SLAB_ * 2);     // xg
    pad((size_t)g * SLAB_ * 4);           // Yw  (fp32)
    pad((size_t)g * SLAB_ * 2);           // tbuf
    pad((size_t)g * SLAB_ * 2);           // curT
    pad((size_t)g * SLAB_ * 4);           // maxT (fp32)
    pad(128 * 256 * 2);                   // Wt
    pad(27 * 8192 * 2);                   // gwT
    if (need <= ws_size) { G = g; break; }
  }

  char* ws = (char*)d_ws;
  int* flag = (int*)ws;
  size_t off = 256;
  auto allocB = [&](size_t bytes) -> char* {
    char* p = ws + off;
    off += (bytes + 255) & ~(size_t)255;
    return p;
  };
  bf16*  canon = (bf16*) allocB((size_t)OF_END * 2);
  bf16*  xg    = (bf16*) allocB((size_t)(G + 3) * SLAB_ * 2);
  float* Yw    = (float*)allocB((size_t)G * SLAB_ * 4);
  bf16*  tbuf  = (bf16*) allocB((size_t)G * SLAB_ * 2);
  bf16*  curT  = (bf16*) allocB((size_t)G * SLAB_ * 2);
  float* maxT  = (float*)allocB((size_t)G * SLAB_ * 4);
  bf16*  Wt    = (bf16*) allocB(128 * 256 * 2);
  bf16*  gwT   = (bf16*) allocB(27 * 8192 * 2);

  const bf16* adjC  = canon + OF_ADJ;
  const bf16* tembC = canon + OF_TEMB;
  const bf16* sembC = canon + OF_SEMB;
  const bf16* c1wC  = canon + OF_C1W;
  const bf16* c1bC  = canon + OF_C1B;
  const bf16* gwC   = canon + OF_GW;
  const bf16* gbC   = canon + OF_GB;

  k_detect<<<dim3(1), 256, 0, stream>>>(data, flag);
  k_convert<<<dim3(OF_END / 256), 256, 0, stream>>>(adj, temb, semb, conv1w, conv1b,
                                                    gcnw, gcnb, flag, canon);
  k_wprep<<<dim3(992), 256, 0, stream>>>(c1wC, gwC, Wt, gwT);

  for (int wbase = 0; wbase < NW_; wbase += G) {
    const int gc = (NW_ - wbase < G) ? (NW_ - wbase) : G;

    k_prepg<<<dim3(8, 8, gc + 3), 256, 0, stream>>>(data, flag, tembC, sembC, xg, wbase);

    // wing: Yw = adj[:, :3N] @ x[w..w+3)   (fp32 out)
    k_gemm_adj<0><<<dim3(16, 8, gc), 256, 0, stream>>>(adjC, xg, nullptr, Yw, nullptr, 3072);

    for (int j = 0; j < 3; j++) {
      const bf16* Bop = (j == 0) ? (xg + 3 * SLAB_) : curT;
      k_gemm_adj<1><<<dim3(16, 8, gc), 256, 0, stream>>>(adjC + 3072, Bop, Yw, nullptr, tbuf, 1024);
      k_zglu<<<dim3(256, 1, gc), 256, 0, stream>>>(tbuf, gwT, gbC, curT, maxT, j, wbase);
    }

    k_final<<<dim3(8, 32, gc), 256, 0, stream>>>(data, flag, Wt, c1bC, maxT, out, wbase);
  }
}